// Round 1
// baseline (131.596 us; speedup 1.0000x reference)
//
#include <hip/hip_runtime.h>
#include <hip/hip_bf16.h>

// DCNv2 forward: B=2, C=256, H=W=96, O=256, K=3x3, stride=1, pad=1, dil=1.
// Pipeline:
//  K1 prep     : (a) input NCHW fp32 -> NHWC bf16,
//                (b) weight -> bf16 32x32-FRAGMENT order wt[kk][cc16][osub][lane][8]
//  K2 dcn_main : cross-tap software pipeline (T14): while computing tap k's
//                16 MFMA chunks, tap k+1's 16 corner loads are in flight and
//                its bilinear+LDS-write lands in the free half of the double
//                buffer. Chunk loop has depth-3 register prefetch of W (global,
//                L2-resident) and B (LDS) via rotating 4-slot arrays.
// R6 theory: latency-serialization-bound (all pipes <23%, 2.25 blk/CU) —
//            1-deep chunk prefetch exposed ~200cyc L2 latency per chunk and
//            fill consumed corner loads immediately after issue.

#define Hh 96
#define Ww 96
#define Cc 256
#define Oo 256
#define Bb 2
#define Kk 9
#define Ss (Hh * Ww)          // 9216
#define CKTOT (Cc * Kk)       // 2304

typedef __bf16 bf16x8 __attribute__((ext_vector_type(8)));
typedef __bf16 bf16x2v __attribute__((ext_vector_type(2)));
typedef float f32x16 __attribute__((ext_vector_type(16)));
typedef float f32x2 __attribute__((ext_vector_type(2)));

__device__ __forceinline__ f32x2 up2(unsigned u) {
  f32x2 r;
  r.x = __uint_as_float(u << 16);
  r.y = __uint_as_float(u & 0xffff0000u);
  return r;
}

// barrier with LDS drain only — prefetched global loads stay in flight.
// simm16 0xC07F = lgkmcnt(0), expcnt(0), vmcnt(63)=no-wait.
__device__ __forceinline__ void barrier_lgkm() {
  asm volatile("" ::: "memory");
  __builtin_amdgcn_s_waitcnt(0xC07F);
  __builtin_amdgcn_s_barrier();
  asm volatile("" ::: "memory");
}

// ---------------- K1: merged prep ----------------
// blocks [0,1152)    : transpose NCHW fp32 -> NHWC bf16
// blocks [1152,3456) : weight repack to 32x32 A-fragment order:
//   wt[kk][cc][osub][lane][j]: o = osub*32 + (lane&31), ch = cc*16 + (lane>>5)*8 + j
__global__ __launch_bounds__(256) void prep(const float* __restrict__ inp,
                                            const float* __restrict__ wsrc,
                                            __bf16* __restrict__ it,
                                            __bf16* __restrict__ wt) {
  __shared__ float tile[64][65];
  const int bx = blockIdx.x;
  const int tid = threadIdx.x;

  if (bx < 1152) {
    const int hw0 = (bx % 144) * 64;
    const int c0 = ((bx / 144) & 3) * 64;
    const int b = bx / 576;
    const int hw_l = tid & 63, cr = tid >> 6;
    const float* src = inp + ((size_t)(b * Cc + c0) * Ss) + hw0;
#pragma unroll
    for (int r = 0; r < 16; ++r) {
      int c_l = r * 4 + cr;
      tile[c_l][hw_l] = src[(size_t)c_l * Ss + hw_l];
    }
    __syncthreads();
    const int cp = (tid & 31) * 2, hr = tid >> 5;
    __bf16* dst = it + ((size_t)(b * Ss + hw0) * Cc) + c0;
#pragma unroll
    for (int r = 0; r < 8; ++r) {
      int hw_s = r * 8 + hr;
      bf16x2v p;
      p.x = (__bf16)tile[cp][hw_s];
      p.y = (__bf16)tile[cp + 1][hw_s];
      *(bf16x2v*)(dst + (size_t)hw_s * Cc + cp) = p;
    }
  } else {
    int i = (bx - 1152) * 256 + tid;  // i < Oo*CKTOT = 589824
    int j = i & 7;
    int l = (i >> 3) & 63;
    int osub = (i >> 9) & 7;
    int cc = (i >> 12) & 15;
    int kk = i >> 16;
    int o = osub * 32 + (l & 31);
    int ch = cc * 16 + ((l >> 5) << 3) + j;
    wt[i] = (__bf16)wsrc[(o * Cc + ch) * Kk + kk];
  }
}

// ---- corner-load half: 2 granule groups x 4 corners = 8 x uint4 (32 VGPR) ----
__device__ __forceinline__ void issue_half(const __bf16* __restrict__ itb,
                                           const int4 a, int fg, int h,
                                           uint4 (&c)[2][4]) {
#pragma unroll
  for (int t = 0; t < 2; ++t) {
    const __bf16* p = itb + (fg + (h * 2 + t) * 8) * 8;
    c[t][0] = *(const uint4*)(p + a.x);
    c[t][1] = *(const uint4*)(p + a.y);
    c[t][2] = *(const uint4*)(p + a.z);
    c[t][3] = *(const uint4*)(p + a.w);
  }
}

__device__ __forceinline__ void proc_half(const float4 wq, int fg, int fs, int h,
                                          const uint4 (&c)[2][4],
                                          __bf16* __restrict__ drow) {
#pragma unroll
  for (int t = 0; t < 2; ++t) {
    int g = fg + (h * 2 + t) * 8;  // logical granule (8 ch)
    unsigned u0[4] = {c[t][0].x, c[t][0].y, c[t][0].z, c[t][0].w};
    unsigned u1[4] = {c[t][1].x, c[t][1].y, c[t][1].z, c[t][1].w};
    unsigned u2[4] = {c[t][2].x, c[t][2].y, c[t][2].z, c[t][2].w};
    unsigned u3[4] = {c[t][3].x, c[t][3].y, c[t][3].z, c[t][3].w};
    bf16x8 rv;
#pragma unroll
    for (int w = 0; w < 4; ++w) {
      f32x2 r = up2(u0[w]) * wq.x + up2(u1[w]) * wq.y +
                up2(u2[w]) * wq.z + up2(u3[w]) * wq.w;
      rv[2 * w] = (__bf16)r.x;
      rv[2 * w + 1] = (__bf16)r.y;
    }
    *(bf16x8*)(drow + ((g ^ (fs & 7)) << 3)) = rv;
  }
}

// ---------------- K2: fused sample + GEMM ----------------
// grid (288, 2): x = 32-s tile (XCD-swizzled), y = batch.
// 256 thr = 4 waves; wave wv covers o in [wv*64, wv*64+64); block = 32s x 256 O.
__global__ __launch_bounds__(256, 2) void dcn_main(
    const __bf16* __restrict__ it,     // [B][S][C] bf16
    const __bf16* __restrict__ wt,     // 32x32-fragment-order weights
    const float* __restrict__ offset,  // [B][18][S]
    const float* __restrict__ mask,    // [B][9][S]
    const float* __restrict__ bias,    // [O]
    float* __restrict__ out)           // [B][O][S]
{
  __shared__ __bf16 colT[2][32 * 256];  // dbuf tap tile, XOR-swizzled granules
  __shared__ int4 pa9[9][32];           // per-tap corner offsets (elements)
  __shared__ float4 pw9[9][32];         // per-tap corner weights (mask+valid folded)

  const int tid = threadIdx.x;
  // XCD swizzle: XCD j gets 36 contiguous 32-s tiles (~2.6MB L2 working set).
  const int tile = (blockIdx.x & 7) * 36 + (blockIdx.x >> 3);
  const int s0 = tile * 32;
  const int b = blockIdx.y;
  const int lane = tid & 63;
  const int wv = tid >> 6;            // 4 waves -> 64 O each
  const int sB = lane & 31;           // B-frag / C-frag spatial lane
  const int hi = lane >> 5;
  const int fs = tid >> 3;            // fill: s-row 0..31
  const int fg = tid & 7;             // fill: granule group 0..7

  const __bf16* itb = it + (size_t)b * Ss * Cc;

  // ---- bilinear params for all 9 taps up front ----
  for (int idx = tid; idx < 9 * 32; idx += 256) {
    int kk = idx >> 5;
    int sl = idx & 31;
    int s = s0 + sl;
    int ho = s / Ww;
    int wo = s - ho * Ww;
    float dy = offset[((size_t)(b * 18 + 2 * kk)) * Ss + s];
    float dx = offset[((size_t)(b * 18 + 2 * kk + 1)) * Ss + s];
    float m = mask[((size_t)(b * 9 + kk)) * Ss + s];
    float y = (float)(ho - 1 + kk / 3) + dy;
    float x = (float)(wo - 1 + kk % 3) + dx;
    float fy = floorf(y), fx = floorf(x);
    int y0 = (int)fy, x0 = (int)fx;
    float wy = y - fy, wx = x - fx;
    int y1 = y0 + 1, x1 = x0 + 1;
    float vy0 = (y0 >= 0 && y0 < Hh) ? 1.f : 0.f;
    float vy1 = (y1 >= 0 && y1 < Hh) ? 1.f : 0.f;
    float vx0 = (x0 >= 0 && x0 < Ww) ? 1.f : 0.f;
    float vx1 = (x1 >= 0 && x1 < Ww) ? 1.f : 0.f;
    int y0c = min(max(y0, 0), Hh - 1), y1c = min(max(y1, 0), Hh - 1);
    int x0c = min(max(x0, 0), Ww - 1), x1c = min(max(x1, 0), Ww - 1);
    pa9[kk][sl] = make_int4((y0c * Ww + x0c) * Cc, (y0c * Ww + x1c) * Cc,
                            (y1c * Ww + x0c) * Cc, (y1c * Ww + x1c) * Cc);
    pw9[kk][sl] = make_float4(m * (1.f - wy) * (1.f - wx) * vy0 * vx0,
                              m * (1.f - wy) * wx * vy0 * vx1,
                              m * wy * (1.f - wx) * vy1 * vx0,
                              m * wy * wx * vy1 * vx1);
  }
  __syncthreads();

  f32x16 acc0, acc1;
#pragma unroll
  for (int j = 0; j < 16; ++j) { acc0[j] = 0.f; acc1[j] = 0.f; }

  // weight A-fragment load: wt[((kk*16+cc)*8 + osub)*512 + lane*8]
  auto ldW = [&](int kk, int cc, int which) {
    size_t idx = (size_t)((kk * 16 + cc) * 8 + wv * 2 + which);
    return *(const bf16x8*)(wt + (idx << 9) + (lane << 3));
  };
  // B fragment from LDS: row sB, logical granule 2cc+hi, XOR-swizzled
  auto ldB = [&](int buf, int cc) {
    int g = ((2 * cc + hi) ^ (sB & 7)) << 3;
    return *(const bf16x8*)(&colT[buf][sB * 256 + g]);
  };

  bf16x8 Wa[4], Wb[4], Bv[4];
  uint4 cA[2][4], cB[2][4];

  // ---- prologue: fill tap 0 (latency exposed once), issue tap-0 chunk-0/1 W ----
  {
    int4 a0 = pa9[0][fs];
    float4 w0 = pw9[0][fs];
    issue_half(itb, a0, fg, 0, cA);
    issue_half(itb, a0, fg, 1, cB);
    proc_half(w0, fg, fs, 0, cA, &colT[0][fs * 256]);
    proc_half(w0, fg, fs, 1, cB, &colT[0][fs * 256]);
  }
  Wa[0] = ldW(0, 0, 0); Wb[0] = ldW(0, 0, 1);
  Wa[1] = ldW(0, 1, 0); Wb[1] = ldW(0, 1, 1);
  barrier_lgkm();

// one MFMA chunk with depth-3 rotating prefetch (all indices compile-time)
#define STEP(cc)                                                               \
  {                                                                            \
    if ((cc) < 13) {                                                           \
      Wa[((cc) + 3) & 3] = ldW(kk, (cc) + 3, 0);                               \
      Wb[((cc) + 3) & 3] = ldW(kk, (cc) + 3, 1);                               \
      Bv[((cc) + 3) & 3] = ldB(buf, (cc) + 3);                                 \
    }                                                                          \
    acc0 = __builtin_amdgcn_mfma_f32_32x32x16_bf16(Wa[(cc) & 3], Bv[(cc) & 3], \
                                                   acc0, 0, 0, 0);             \
    acc1 = __builtin_amdgcn_mfma_f32_32x32x16_bf16(Wb[(cc) & 3], Bv[(cc) & 3], \
                                                   acc1, 0, 0, 0);             \
  }

  for (int kk = 0; kk < Kk; ++kk) {
    const int buf = kk & 1;
    // issue next tap's first corner half — in flight across chunks 0..7
    int4 na;
    float4 nwq;
    if (kk < 8) {
      na = pa9[kk + 1][fs];
      issue_half(itb, na, fg, 0, cA);
    }
    // finish chunk prefetch init (B needs the barrier; W slot 2 from global)
    Bv[0] = ldB(buf, 0);
    Bv[1] = ldB(buf, 1);
    Bv[2] = ldB(buf, 2);
    Wa[2] = ldW(kk, 2, 0);
    Wb[2] = ldW(kk, 2, 1);

    STEP(0) STEP(1) STEP(2) STEP(3) STEP(4) STEP(5) STEP(6) STEP(7)

    if (kk < 8) {
      // corner half A has had ~8 chunks of cover: process into free buffer,
      // then launch half B to fly across chunks 8..15.
      nwq = pw9[kk + 1][fs];
      proc_half(nwq, fg, fs, 0, cA, &colT[buf ^ 1][fs * 256]);
      issue_half(itb, na, fg, 1, cB);
    }

    STEP(8) STEP(9) STEP(10) STEP(11) STEP(12) STEP(13) STEP(14) STEP(15)

    if (kk < 8) {
      proc_half(nwq, fg, fs, 1, cB, &colT[buf ^ 1][fs * 256]);
      // next tap's chunk-0/1 weights issued pre-barrier, stay in flight
      Wa[0] = ldW(kk + 1, 0, 0); Wb[0] = ldW(kk + 1, 0, 1);
      Wa[1] = ldW(kk + 1, 1, 0); Wb[1] = ldW(kk + 1, 1, 1);
    }
    barrier_lgkm();
  }
#undef STEP

  // ---- epilogue: direct store with bias ----
  // D mapping (32x32): col(s)=lane&31, row(o-off)=(r&3)+8*(r>>2)+4*(lane>>5)
  float* ob = out + (size_t)b * Oo * Ss + s0 + sB;
#pragma unroll
  for (int os = 0; os < 2; ++os) {
#pragma unroll
    for (int r = 0; r < 16; ++r) {
      int o = wv * 64 + os * 32 + (r & 3) + 8 * (r >> 2) + 4 * hi;
      float v = (os ? acc1[r] : acc0[r]) + bias[o];
      ob[(size_t)o * Ss] = v;
    }
  }
}

extern "C" void kernel_launch(void* const* d_in, const int* in_sizes, int n_in,
                              void* d_out, int out_size, void* d_ws, size_t ws_size,
                              hipStream_t stream) {
  (void)in_sizes; (void)n_in; (void)out_size; (void)ws_size;
  const float* inp = (const float*)d_in[0];
  const float* offset = (const float*)d_in[1];
  const float* mask = (const float*)d_in[2];
  const float* weight = (const float*)d_in[3];
  const float* bias = (const float*)d_in[4];
  float* out = (float*)d_out;

  __bf16* it = (__bf16*)d_ws;                                      // 9,437,184 B
  __bf16* wt = (__bf16*)((char*)d_ws + (size_t)Bb * Ss * Cc * 2);  // 1,179,648 B

  prep<<<3456, 256, 0, stream>>>(inp, weight, it, wt);
  dcn_main<<<dim3(288, Bb), 256, 0, stream>>>(it, wt, offset, mask, bias, out);
}